// Round 1
// 379.032 us; speedup vs baseline: 1.0206x; 1.0206x over previous
//
#include <hip/hip_runtime.h>
#include <math.h>

#pragma clang fp contract(off)

#define NPTS 4096
#define PTS  32768
#define ROWS 163840   // PTS * 5
#define QN   16       // candidate slices per batch
#define QLEN 256      // NPTS / QN
#define SLOTS 8       // packed top-k slots per slice (and global survivors)

// LAPACK single-precision machine constants (gfortran/IEEE):
#define EPS_L   5.9604644775390625e-8f    // 2^-24  SLAMCH('E')
#define EPS2_L  3.5527136788005009e-15f   // 2^-48
#define SAFMIN_L 1.1754943508222875e-38f  // 2^-126

// Round-to-nearest, non-contractible f32 ops (file pragma disables fusion).
__device__ __forceinline__ float frn_mul(float a, float b) { float r = a * b; return r; }
__device__ __forceinline__ float frn_add(float a, float b) { float r = a + b; return r; }
__device__ __forceinline__ float frn_sub(float a, float b) { float r = a - b; return r; }
__device__ __forceinline__ float frn_div(float a, float b) { float r = a / b; return r; }

__device__ __forceinline__ float ref_sq(float x0, float x1) {
  return frn_add(frn_mul(x0, x0), frn_mul(x1, x1));
}
// dist_sq[n,m] = fl( fl(sq_n + sq_m) - 2*dot ), dot = fma(ny*my, fl(nx*mx)).
__device__ __forceinline__ float ref_key(float nx, float ny, float sqn,
                                         float mx, float my, float sqm) {
  float dot = fmaf(ny, my, frn_mul(nx, mx));
  float s = frn_add(sqn, sqm);
  return fmaf(-2.0f, dot, s);
}

// ---------------------------------------------------------------------------
// Weight transpose prep, zero-padded K stride: wt[j*Kp + i] = (i<K)? w[i*N+j]:0
// ---------------------------------------------------------------------------
__global__ __launch_bounds__(256) void prep_w(
    const float* __restrict__ lw1, const float* __restrict__ lw2, const float* __restrict__ lw3,
    const float* __restrict__ cw1, const float* __restrict__ cw2,
    const float* __restrict__ tw1, const float* __restrict__ tw2,
    float* __restrict__ wt) {
  const int Ks[7]   = {2, 64, 128, 66, 128, 64, 128};
  const int Kp[7]   = {2, 64, 128, 80, 128, 64, 128};
  const int Ns[7]   = {64, 128, 64, 128, 128, 128, 128};
  const int offs[7] = {0, 128, 8320, 16512, 26752, 43136, 51328};
  const float* srcs[7] = {lw1, lw2, lw3, cw1, cw2, tw1, tw2};
  int b = blockIdx.x;
  const float* src = srcs[b];
  float* dst = wt + offs[b];
  int K = Ks[b], KP = Kp[b], N = Ns[b];
  for (int e = threadIdx.x; e < KP * N; e += 256) {
    int j = e / KP, i = e - j * KP;
    dst[e] = (i < K) ? src[i * N + j] : 0.0f;
  }
}

// ---------------------------------------------------------------------------
// kNN scan: 2048 blocks = 128 point-groups x 16 candidate-slices (8/CU,
// 18 KB LDS). Threshold-filtered top-8, unroll-4:
// candidates cost ~1 cmp + UNCONDITIONAL buffered append (a failing write
// lands in slot cnt, which only becomes readable when a passing value
// overwrites it) — no trash row, no cndmask. Flush-check every 4 candidates
// with threshold cnt>=13 (start-of-iter cnt<=12, +4 appends -> slots <= 15).
// Packed value = (bits(dist)&0xFFFFF000)|idx (direct dist >= 0 u32-monotone).
// Monotone threshold T => no true top-8 element dropped (values distinct by
// idx); exact ref-key re-rank happens in merge_geom. Flush batching order is
// immaterial: the bubble network keeps the 8 smallest of all flushed values.
// ---------------------------------------------------------------------------
__device__ __forceinline__ void cand_step(float mex, float mey, float cx, float cy,
                                          unsigned int idx, unsigned int T,
                                          unsigned int* sbuf, int t,
                                          unsigned int& cnt) {
  float dx = mex - cx, dy = mey - cy;
  float dist = fmaf(dy, dy, dx * dx);
  unsigned int v = (__float_as_uint(dist) & 0xFFFFF000u) | idx;
  sbuf[cnt * 256 + t] = v;
  cnt += (v < T) ? 1u : 0u;
}

__global__ __launch_bounds__(256) void knn_scan(const float* __restrict__ x,
                                                unsigned int* __restrict__ ipart) {
  __shared__ float2 cand[QLEN];            // 2 KB
  __shared__ unsigned int sbuf[16 * 256];  // 16 KB survivor buffer
  int bx = blockIdx.x;
  int q = bx & (QN - 1);
  int pg = bx >> 4;
  int batch = pg >> 4;
  const float* xb = x + (size_t)batch * NPTS * 2;
  int c0 = q * QLEN;
  for (int i = threadIdx.x; i < QLEN; i += 256)
    cand[i] = ((const float2*)xb)[c0 + i];
  __syncthreads();
  int t = threadIdx.x;
  int p = pg * 256 + t;
  float2 me = ((const float2*)x)[p];
  unsigned int d[SLOTS];
#pragma unroll
  for (int s = 0; s < SLOTS; s++) d[s] = 0xFFFFFFFFu;
  unsigned int T = 0xFFFFFFFFu;
  unsigned int cnt = 0;
  for (int mm = 0; mm < QLEN / 4; mm++) {
    float4 c01 = ((const float4*)cand)[2 * mm];
    float4 c23 = ((const float4*)cand)[2 * mm + 1];
    unsigned int idx0 = (unsigned int)(c0 + 4 * mm);
    cand_step(me.x, me.y, c01.x, c01.y, idx0 + 0u, T, sbuf, t, cnt);
    cand_step(me.x, me.y, c01.z, c01.w, idx0 + 1u, T, sbuf, t, cnt);
    cand_step(me.x, me.y, c23.x, c23.y, idx0 + 2u, T, sbuf, t, cnt);
    cand_step(me.x, me.y, c23.z, c23.w, idx0 + 3u, T, sbuf, t, cnt);
    if (__any((int)(cnt >= 13u))) {
#pragma unroll
      for (int j = 0; j < 16; j++) {
        unsigned int u = ((unsigned)j < cnt) ? sbuf[j * 256 + t] : 0xFFFFFFFFu;
#pragma unroll
        for (int s = 0; s < SLOTS; s++) {
          unsigned int lo = min(u, d[s]);
          unsigned int hi = max(u, d[s]);
          d[s] = lo; u = hi;
        }
      }
      cnt = 0;
      T = d[SLOTS - 1];
    }
  }
  // final flush of residual buffer entries
#pragma unroll
  for (int j = 0; j < 16; j++) {
    unsigned int u = ((unsigned)j < cnt) ? sbuf[j * 256 + t] : 0xFFFFFFFFu;
#pragma unroll
    for (int s = 0; s < SLOTS; s++) {
      unsigned int lo = min(u, d[s]);
      unsigned int hi = max(u, d[s]);
      d[s] = lo; u = hi;
    }
  }
#pragma unroll
  for (int s = 0; s < SLOTS; s++)
    ipart[((size_t)(q * SLOTS + s)) * PTS + p] = d[s];
}

// ---------------------------------------------------------------------------
// Merge + geometry. Gathers 128 packed survivors -> packed top-8 -> exact
// (f32 ref key, idx) lex re-rank -> reference top-5 -> covariance ->
// ssteqr/SLAEV2 replica -> angle/axes + interleaved lcc (float2).
// 256 blocks x 128 threads (full GPU; layer-1 fused into gemm_l2).
// ---------------------------------------------------------------------------
__global__ __launch_bounds__(128) void merge_geom(const float* __restrict__ x,
    const unsigned int* __restrict__ ipart,
    float2* __restrict__ lcct2,
    float* __restrict__ angle_out, float2* __restrict__ axes_out) {
  int p = blockIdx.x * 128 + threadIdx.x;
  int batch = p >> 12;
  const float2* xb = (const float2*)(x + (size_t)batch * NPTS * 2);
  float2 me = ((const float2*)x)[p];
  float sqn = ref_sq(me.x, me.y);

  unsigned int g[SLOTS];
#pragma unroll
  for (int s = 0; s < SLOTS; s++) g[s] = 0xFFFFFFFFu;
  for (int qs = 0; qs < QN * SLOTS; qs++) {
    unsigned int v = ipart[(size_t)qs * PTS + p];
#pragma unroll
    for (int s = 0; s < SLOTS; s++) {
      unsigned int lo = min(v, g[s]);
      unsigned int hi = max(v, g[s]);
      g[s] = lo; v = hi;
    }
  }
  float dk[5]; int id[5];
#pragma unroll
  for (int s = 0; s < 5; s++) { dk[s] = 3.0e38f; id[s] = 0x7fffffff; }
#pragma unroll
  for (int s8 = 0; s8 < SLOTS; s8++) {
    int ci = (int)(g[s8] & 0xFFFu);
    float2 c = xb[ci];
    float key = ref_key(me.x, me.y, sqn, c.x, c.y, ref_sq(c.x, c.y));
    float v = key; int vi = ci;
#pragma unroll
    for (int s = 0; s < 5; s++) {
      bool lt = (v < dk[s]) || (v == dk[s] && vi < id[s]);
      float tv = dk[s]; int ti = id[s];
      if (lt) { dk[s] = v; id[s] = vi; v = tv; vi = ti; }
    }
  }
  float rx[5], ry[5];
  float sx = 0.f, sy = 0.f;
#pragma unroll
  for (int k = 0; k < 5; k++) {
    float2 nb = xb[id[k]];
    rx[k] = frn_sub(nb.x, me.x); ry[k] = frn_sub(nb.y, me.y);
    sx = frn_add(sx, rx[k]); sy = frn_add(sy, ry[k]);
  }
  float mx = frn_div(sx, 5.0f), my = frn_div(sy, 5.0f);
  float c00 = 0.f, c01 = 0.f, c11 = 0.f;
#pragma unroll
  for (int k = 0; k < 5; k++) {
    rx[k] = frn_sub(rx[k], mx); ry[k] = frn_sub(ry[k], my);
    c00 = frn_add(c00, frn_mul(rx[k], rx[k]));
    c01 = frn_add(c01, frn_mul(rx[k], ry[k]));
    c11 = frn_add(c11, frn_mul(ry[k], ry[k]));
  }
  c00 = frn_div(c00, 4.0f); c01 = frn_div(c01, 4.0f); c11 = frn_div(c11, 4.0f);
  float A = frn_add(c00, 1e-6f), Bv = c01, C = frn_add(c11, 1e-6f);

  // ---- ssteqr 2x2 replica ----
  float absA = fabsf(A), absC = fabsf(C), absB = fabsf(Bv);
  float thr = frn_mul(frn_mul(sqrtf(absA), sqrtf(absC)), EPS_L);
  bool diag = (absB == 0.f) || (absB <= thr);
  if (!diag) {
    bool qr = (absC < absA);
    float b2 = frn_mul(absB, absB);
    float t = qr ? frn_add(frn_mul(frn_mul(EPS2_L, absC), absA), SAFMIN_L)
                 : frn_add(frn_mul(frn_mul(EPS2_L, absA), absC), SAFMIN_L);
    if (b2 <= t) diag = true;
  }
  float e1, e2, v00, v10, v01, v11;
  if (diag) {
    if (C < A) { e1 = C; e2 = A; v00 = 0.f; v10 = 1.f; v01 = 1.f; v11 = 0.f; }
    else       { e1 = A; e2 = C; v00 = 1.f; v10 = 0.f; v01 = 0.f; v11 = 1.f; }
  } else {
    // ---- SLAEV2 replica ----
    float sm = frn_add(A, C), df = frn_sub(A, C);
    float adf = fabsf(df), tb = frn_add(Bv, Bv), ab = fabsf(tb);
    float rt;
    if (adf > ab) {
      float r = frn_div(ab, adf);
      rt = frn_mul(adf, sqrtf(frn_add(1.0f, frn_mul(r, r))));
    } else if (adf < ab) {
      float r = frn_div(adf, ab);
      rt = frn_mul(ab, sqrtf(frn_add(1.0f, frn_mul(r, r))));
    } else {
      rt = frn_mul(ab, sqrtf(2.0f));
    }
    float acmx, acmn;
    if (absA > absC) { acmx = A; acmn = C; } else { acmx = C; acmn = A; }
    float rt1, rt2; int sgn1;
    if (sm < 0.f) {
      rt1 = frn_mul(0.5f, frn_sub(sm, rt)); sgn1 = -1;
      rt2 = frn_sub(frn_mul(frn_div(acmx, rt1), acmn), frn_mul(frn_div(Bv, rt1), Bv));
    } else if (sm > 0.f) {
      rt1 = frn_mul(0.5f, frn_add(sm, rt)); sgn1 = 1;
      rt2 = frn_sub(frn_mul(frn_div(acmx, rt1), acmn), frn_mul(frn_div(Bv, rt1), Bv));
    } else {
      rt1 = frn_mul(0.5f, rt); rt2 = frn_mul(-0.5f, rt); sgn1 = 1;
    }
    float cs, cs1, sn1; int sgn2;
    if (df >= 0.f) { cs = frn_add(df, rt); sgn2 = 1; }
    else           { cs = frn_sub(df, rt); sgn2 = -1; }
    float acs = fabsf(cs);
    if (acs > ab) {
      float ct = frn_div(-tb, cs);
      sn1 = frn_div(1.0f, sqrtf(frn_add(1.0f, frn_mul(ct, ct))));
      cs1 = frn_mul(ct, sn1);
    } else {
      if (ab == 0.f) { cs1 = 1.0f; sn1 = 0.0f; }
      else {
        float tn = frn_div(-cs, tb);
        cs1 = frn_div(1.0f, sqrtf(frn_add(1.0f, frn_mul(tn, tn))));
        sn1 = frn_mul(tn, cs1);
      }
    }
    if (sgn1 == sgn2) { float t = cs1; cs1 = -sn1; sn1 = t; }
    if (rt2 < rt1) { e1 = rt2; e2 = rt1; v00 = -sn1; v10 = cs1; v01 = cs1;  v11 = sn1; }
    else           { e1 = rt1; e2 = rt2; v00 = cs1;  v10 = sn1; v01 = -sn1; v11 = cs1; }
  }

  angle_out[p] = atan2f(v11, v01);
  float aM = sqrtf(fmaxf(e2, 1e-6f));
  float am = sqrtf(fmaxf(e1, 1e-6f));
  float den = frn_add(fmaxf(aM, am), 1e-6f);
  axes_out[p] = make_float2(fmaxf(frn_div(aM, den), 0.2f),
                            fmaxf(frn_div(am, den), 0.2f));

  size_t rowb = (size_t)p * 5;
#pragma unroll
  for (int k = 0; k < 5; k++) {
    float l0 = frn_add(frn_mul(rx[k], v00), frn_mul(ry[k], v10));
    float l1 = frn_add(frn_mul(rx[k], v01), frn_mul(ry[k], v11));
    lcct2[rowb + k] = make_float2(l0, l1);
  }
}

// ---------------------------------------------------------------------------
// Fused layer1+layer2: out[n][m] = relu(lb2[n] + sum_k relu(h1[k][m]) * w2..)
// where h1[k][m] = fmaf(l.y, lw1t[2k+1], fmaf(l.x, lw1t[2k], lb1[k])) is
// computed into the A-tile LDS from lcct2 (no h1 round-trip through HBM).
// fma chain identical to the previously-separate dense1 (bit-exact A-tile).
// MB=NB=128, KB=16, KTILES=4, Kstr(w)=64.
// ---------------------------------------------------------------------------
__global__ __launch_bounds__(256, 3) void gemm_l2(
    const float2* __restrict__ lcct2, const float* __restrict__ lw1t,
    const float* __restrict__ lb1,
    const float* __restrict__ wt, const float* __restrict__ bias,
    float* __restrict__ out_t, int M) {
  __shared__ float alds[16 * 128];
  __shared__ float wlds[16 * 128];
  __shared__ float w1s[192];  // [0..127]=lw1t (64 pairs), [128..191]=lb1
  int t = threadIdx.x;
  int m0 = blockIdx.x * 128;
  if (t < 192) w1s[t] = (t < 128) ? lw1t[t] : lb1[t - 128];
  int mloc = t & 127;
  int kbase = t >> 7;  // 0 or 1 (wave-uniform)
  float2 lme = lcct2[m0 + mloc];
  int tm = t & 15;
  int tn = t >> 4;
  float acc[8][8];
#pragma unroll
  for (int j = 0; j < 8; j++) {
    float b = bias[tn * 8 + j];
#pragma unroll
    for (int i = 0; i < 8; i++) acc[j][i] = b;
  }
  for (int kt = 0; kt < 4; kt++) {
    int k0 = kt * 16;
    __syncthreads();
    // A-stage: compute h1 tile in place of a global load.
#pragma unroll
    for (int pp = 0; pp < 8; pp++) {
      int kk = pp * 2 + kbase;
      int k = k0 + kk;
      float h = fmaf(lme.y, w1s[2 * k + 1], fmaf(lme.x, w1s[2 * k], w1s[128 + k]));
      alds[kk * 128 + mloc] = fmaxf(h, 0.f);
    }
    // W-stage (WPASS = 2, Kstr = 64)
#pragma unroll
    for (int pp = 0; pp < 2; pp++) {
      int e = pp * 256 + t;
      int n = e >> 2;
      int kc = e & 3;
      float4 v = *(const float4*)(wt + (size_t)n * 64 + k0 + kc * 4);
      wlds[(kc * 4 + 0) * 128 + n] = v.x;
      wlds[(kc * 4 + 1) * 128 + n] = v.y;
      wlds[(kc * 4 + 2) * 128 + n] = v.z;
      wlds[(kc * 4 + 3) * 128 + n] = v.w;
    }
    __syncthreads();
#pragma unroll
    for (int kk = 0; kk < 16; kk++) {
      float af[8], wf[8];
      *(float4*)(af)     = *(const float4*)(alds + kk * 128 + tm * 8);
      *(float4*)(af + 4) = *(const float4*)(alds + kk * 128 + tm * 8 + 4);
      *(float4*)(wf)     = *(const float4*)(wlds + kk * 128 + tn * 8);
      *(float4*)(wf + 4) = *(const float4*)(wlds + kk * 128 + tn * 8 + 4);
#pragma unroll
      for (int j = 0; j < 8; j++)
#pragma unroll
        for (int i = 0; i < 8; i++)
          acc[j][i] = fmaf(af[i], wf[j], acc[j][i]);
    }
  }
#pragma unroll
  for (int j = 0; j < 8; j++) {
    int n = tn * 8 + j;
    float4 o0, o1;
    o0.x = fmaxf(acc[j][0], 0.f); o0.y = fmaxf(acc[j][1], 0.f);
    o0.z = fmaxf(acc[j][2], 0.f); o0.w = fmaxf(acc[j][3], 0.f);
    o1.x = fmaxf(acc[j][4], 0.f); o1.y = fmaxf(acc[j][5], 0.f);
    o1.z = fmaxf(acc[j][6], 0.f); o1.w = fmaxf(acc[j][7], 0.f);
    float* dst = out_t + (size_t)n * M + m0 + tm * 8;
    *(float4*)(dst) = o0;
    *(float4*)(dst + 4) = o1;
  }
}

// ---------------------------------------------------------------------------
// Register-tiled fp32 GEMM: out[n][m] = relu(bias[n] + sum_k w[n][k]*in[k][m])
// ---------------------------------------------------------------------------
template <int MB, int NB, int KTILES>
__global__ __launch_bounds__(256, 3) void gemm_f32(
    const float* __restrict__ in_t, const float* __restrict__ wt,
    const float* __restrict__ bias, float* __restrict__ out_t,
    int M, int Kstr) {
  constexpr int KB = 16;
  __shared__ float alds[KB * MB];
  __shared__ float wlds[KB * NB];
  int t = threadIdx.x;
  int m0 = blockIdx.x * MB;
  constexpr int TM = MB / 8;
  constexpr int TMS = (MB == 128) ? 4 : 5;
  int tm = t & (TM - 1);
  int tn = t >> TMS;
  float acc[8][8];
#pragma unroll
  for (int j = 0; j < 8; j++) {
    float b = bias[tn * 8 + j];
#pragma unroll
    for (int i = 0; i < 8; i++) acc[j][i] = b;
  }
  for (int kt = 0; kt < KTILES; kt++) {
    int k0 = kt * KB;
    __syncthreads();
    constexpr int APASS = (KB * MB / 4) / 256;
#pragma unroll
    for (int pp = 0; pp < APASS; pp++) {
      int e = pp * 256 + t;
      int kk = e / (MB / 4);
      int m4 = e - kk * (MB / 4);
      float4 v = *(const float4*)(in_t + (size_t)(k0 + kk) * M + m0 + m4 * 4);
      *(float4*)(alds + kk * MB + m4 * 4) = v;
    }
    constexpr int WPASS = (KB * NB / 4) / 256;
#pragma unroll
    for (int pp = 0; pp < WPASS; pp++) {
      int e = pp * 256 + t;
      int n = e >> 2;
      int kc = e & 3;
      float4 v = *(const float4*)(wt + (size_t)n * Kstr + k0 + kc * 4);
      wlds[(kc * 4 + 0) * NB + n] = v.x;
      wlds[(kc * 4 + 1) * NB + n] = v.y;
      wlds[(kc * 4 + 2) * NB + n] = v.z;
      wlds[(kc * 4 + 3) * NB + n] = v.w;
    }
    __syncthreads();
#pragma unroll
    for (int kk = 0; kk < KB; kk++) {
      float af[8], wf[8];
      *(float4*)(af)     = *(const float4*)(alds + kk * MB + tm * 8);
      *(float4*)(af + 4) = *(const float4*)(alds + kk * MB + tm * 8 + 4);
      *(float4*)(wf)     = *(const float4*)(wlds + kk * NB + tn * 8);
      *(float4*)(wf + 4) = *(const float4*)(wlds + kk * NB + tn * 8 + 4);
#pragma unroll
      for (int j = 0; j < 8; j++)
#pragma unroll
        for (int i = 0; i < 8; i++)
          acc[j][i] = fmaf(af[i], wf[j], acc[j][i]);
    }
  }
#pragma unroll
  for (int j = 0; j < 8; j++) {
    int n = tn * 8 + j;
    float4 o0, o1;
    o0.x = fmaxf(acc[j][0], 0.f); o0.y = fmaxf(acc[j][1], 0.f);
    o0.z = fmaxf(acc[j][2], 0.f); o0.w = fmaxf(acc[j][3], 0.f);
    o1.x = fmaxf(acc[j][4], 0.f); o1.y = fmaxf(acc[j][5], 0.f);
    o1.z = fmaxf(acc[j][6], 0.f); o1.w = fmaxf(acc[j][7], 0.f);
    float* dst = out_t + (size_t)n * M + m0 + tm * 8;
    *(float4*)(dst) = o0;
    *(float4*)(dst + 4) = o1;
  }
}

// ---------------------------------------------------------------------------
// Max over K=5 rows -> lftx rows 2..65 ; rows 0..1 = x passthrough.
// ---------------------------------------------------------------------------
__global__ __launch_bounds__(256) void maxpack(const float* __restrict__ h3,
                                               const float* __restrict__ x,
                                               float* __restrict__ lftx) {
  int idx = blockIdx.x * 256 + threadIdx.x;
  int f = idx >> 15;
  int p = idx & (PTS - 1);
  if (f < 64) {
    const float* hr = h3 + (size_t)f * ROWS + (size_t)p * 5;
    float m = fmaxf(fmaxf(fmaxf(hr[0], hr[1]), fmaxf(hr[2], hr[3])), hr[4]);
    lftx[(size_t)(f + 2) * PTS + p] = m;
  } else if (f < 66) {
    int i = f - 64;
    lftx[(size_t)i * PTS + p] = x[(size_t)p * 2 + i];
  }
}

// ---------------------------------------------------------------------------
// Transpose [256][32768] feature-major head outputs into d_out row-major.
// ---------------------------------------------------------------------------
__global__ __launch_bounds__(256) void transpose_out(const float* __restrict__ o_t, float* __restrict__ out) {
  __shared__ float tile[64][65];
  int p0 = blockIdx.x * 64;
  int j0 = blockIdx.y * 64;
  int tc = threadIdx.x & 63, tr = threadIdx.x >> 6;
#pragma unroll
  for (int rr = 0; rr < 16; rr++) {
    int j = tr + rr * 4;
    tile[j][tc] = o_t[(size_t)(j0 + j) * PTS + p0 + tc];
  }
  __syncthreads();
#pragma unroll
  for (int rr = 0; rr < 16; rr++) {
    int pl = tr + rr * 4;
    int p = p0 + pl;
    int j = j0 + tc;
    float v = tile[tc][pl];
    size_t o = (j < 128) ? ((size_t)p * 128 + j)
                         : ((size_t)4194304 + (size_t)p * 128 + (j - 128));
    out[o] = v;
  }
}

// ---------------------------------------------------------------------------
extern "C" void kernel_launch(void* const* d_in, const int* in_sizes, int n_in,
                              void* d_out, int out_size, void* d_ws, size_t ws_size,
                              hipStream_t stream) {
  const float* x   = (const float*)d_in[0];
  const float* lb1 = (const float*)d_in[2];
  const float* lb2 = (const float*)d_in[4];
  const float* lb3 = (const float*)d_in[6];
  const float* cb1 = (const float*)d_in[8];
  const float* cb2 = (const float*)d_in[10];
  const float* tb1 = (const float*)d_in[12];
  const float* tb2 = (const float*)d_in[14];

  float* out = (float*)d_out;
  float* angle_out = out + 8388608;
  float* axes_out  = out + 8421376;

  // Workspace (floats), lifetime-overlapped:
  //   wt    [67712]
  //   R1    [10485760]  ipart (knn->merge, 4M u32) then h3 (l3->maxpack)
  //   R2    [10485760]  a1 (c1->c2, t1->t2)   [h1 eliminated by gemm_l2 fusion]
  //   R3    [20971520]  h2 (l2->l3) then outct+outtt (heads->transpose)
  //   lftx  [2621440]
  //   lcct2 [327680]    interleaved (l0,l1) per row
  float* W = (float*)d_ws;
  float* wt    = W;
  float* R1    = W + 67712;
  float* R2    = R1 + 10485760;
  float* R3    = R2 + 10485760;
  float* lftx  = R3 + 20971520;
  float* lcct2 = lftx + 2621440;
  unsigned int* ipart = (unsigned int*)R1;
  float* h3    = R1;
  float* a1    = R2;
  float* h2    = R3;
  float* outct = R3;
  float* outtt = R3 + 4194304;

  prep_w<<<7, 256, 0, stream>>>((const float*)d_in[1], (const float*)d_in[3], (const float*)d_in[5],
                                (const float*)d_in[7], (const float*)d_in[9],
                                (const float*)d_in[11], (const float*)d_in[13], wt);
  knn_scan<<<2048, 256, 0, stream>>>(x, ipart);
  merge_geom<<<256, 128, 0, stream>>>(x, ipart, (float2*)lcct2, angle_out, (float2*)axes_out);

  gemm_l2<<<ROWS / 128, 256, 0, stream>>>((const float2*)lcct2, wt + 0, lb1,
                                          wt + 128, lb2, h2, ROWS);
  gemm_f32<256, 64, 8><<<ROWS / 256, 256, 0, stream>>>(h2, wt + 8320, lb3, h3, ROWS, 128);
  maxpack<<<(66 * PTS) / 256, 256, 0, stream>>>(h3, x, lftx);

  gemm_f32<128, 128, 5><<<PTS / 128, 256, 0, stream>>>(lftx, wt + 16512, cb1, a1, PTS, 80);
  gemm_f32<128, 128, 8><<<PTS / 128, 256, 0, stream>>>(a1, wt + 26752, cb2, outct, PTS, 128);
  gemm_f32<128, 128, 4><<<PTS / 128, 256, 0, stream>>>(lftx + 2 * PTS, wt + 43136, tb1, a1, PTS, 64);
  gemm_f32<128, 128, 8><<<PTS / 128, 256, 0, stream>>>(a1, wt + 51328, tb2, outtt, PTS, 128);

  transpose_out<<<dim3(512, 4), 256, 0, stream>>>(outct, out);
}

// Round 3
// 350.389 us; speedup vs baseline: 1.1041x; 1.0817x over previous
//
#include <hip/hip_runtime.h>
#include <math.h>

#pragma clang fp contract(off)

#define NPTS 4096
#define PTS  32768
#define ROWS 163840   // PTS * 5
#define QN   16       // candidate slices per batch
#define QLEN 256      // NPTS / QN
#define SLOTS 8       // packed top-k slots per slice (and global survivors)

// LAPACK single-precision machine constants (gfortran/IEEE):
#define EPS_L   5.9604644775390625e-8f    // 2^-24  SLAMCH('E')
#define EPS2_L  3.5527136788005009e-15f   // 2^-48
#define SAFMIN_L 1.1754943508222875e-38f  // 2^-126

// Round-to-nearest, non-contractible f32 ops (file pragma disables fusion).
__device__ __forceinline__ float frn_mul(float a, float b) { float r = a * b; return r; }
__device__ __forceinline__ float frn_add(float a, float b) { float r = a + b; return r; }
__device__ __forceinline__ float frn_sub(float a, float b) { float r = a - b; return r; }
__device__ __forceinline__ float frn_div(float a, float b) { float r = a / b; return r; }

__device__ __forceinline__ float ref_sq(float x0, float x1) {
  return frn_add(frn_mul(x0, x0), frn_mul(x1, x1));
}
// dist_sq[n,m] = fl( fl(sq_n + sq_m) - 2*dot ), dot = fma(ny*my, fl(nx*mx)).
__device__ __forceinline__ float ref_key(float nx, float ny, float sqn,
                                         float mx, float my, float sqm) {
  float dot = fmaf(ny, my, frn_mul(nx, mx));
  float s = frn_add(sqn, sqm);
  return fmaf(-2.0f, dot, s);
}

// ---------------------------------------------------------------------------
// Weight transpose prep, zero-padded K stride: wt[j*Kp + i] = (i<K)? w[i*N+j]:0
// ---------------------------------------------------------------------------
__global__ __launch_bounds__(256) void prep_w(
    const float* __restrict__ lw1, const float* __restrict__ lw2, const float* __restrict__ lw3,
    const float* __restrict__ cw1, const float* __restrict__ cw2,
    const float* __restrict__ tw1, const float* __restrict__ tw2,
    float* __restrict__ wt) {
  const int Ks[7]   = {2, 64, 128, 66, 128, 64, 128};
  const int Kp[7]   = {2, 64, 128, 80, 128, 64, 128};
  const int Ns[7]   = {64, 128, 64, 128, 128, 128, 128};
  const int offs[7] = {0, 128, 8320, 16512, 26752, 43136, 51328};
  const float* srcs[7] = {lw1, lw2, lw3, cw1, cw2, tw1, tw2};
  int b = blockIdx.x;
  const float* src = srcs[b];
  float* dst = wt + offs[b];
  int K = Ks[b], KP = Kp[b], N = Ns[b];
  for (int e = threadIdx.x; e < KP * N; e += 256) {
    int j = e / KP, i = e - j * KP;
    dst[e] = (i < K) ? src[i * N + j] : 0.0f;
  }
}

// ---------------------------------------------------------------------------
// kNN scan: 2048 blocks = 128 point-groups x 16 candidate-slices (8/CU,
// 18 KB LDS). Threshold-filtered top-8, unroll-4:
// candidates cost ~1 cmp + UNCONDITIONAL buffered append (a failing write
// lands in slot cnt, which only becomes readable when a passing value
// overwrites it) — no trash row, no cndmask. Flush-check every 4 candidates
// with threshold cnt>=13 (start-of-iter cnt<=12, +4 appends -> slots <= 15).
// Packed value = (bits(dist)&0xFFFFF000)|idx (direct dist >= 0 u32-monotone).
// Monotone threshold T => no true top-8 element dropped (values distinct by
// idx); exact ref-key re-rank happens in merge_geom. Flush batching order is
// immaterial: the bubble network keeps the 8 smallest of all flushed values.
// ---------------------------------------------------------------------------
__device__ __forceinline__ void cand_step(float mex, float mey, float cx, float cy,
                                          unsigned int idx, unsigned int T,
                                          unsigned int* sbuf, int t,
                                          unsigned int& cnt) {
  float dx = mex - cx, dy = mey - cy;
  float dist = fmaf(dy, dy, dx * dx);
  unsigned int v = (__float_as_uint(dist) & 0xFFFFF000u) | idx;
  sbuf[cnt * 256 + t] = v;
  cnt += (v < T) ? 1u : 0u;
}

__global__ __launch_bounds__(256) void knn_scan(const float* __restrict__ x,
                                                unsigned int* __restrict__ ipart) {
  __shared__ float2 cand[QLEN];            // 2 KB
  __shared__ unsigned int sbuf[16 * 256];  // 16 KB survivor buffer
  int bx = blockIdx.x;
  int q = bx & (QN - 1);
  int pg = bx >> 4;
  int batch = pg >> 4;
  const float* xb = x + (size_t)batch * NPTS * 2;
  int c0 = q * QLEN;
  for (int i = threadIdx.x; i < QLEN; i += 256)
    cand[i] = ((const float2*)xb)[c0 + i];
  __syncthreads();
  int t = threadIdx.x;
  int p = pg * 256 + t;
  float2 me = ((const float2*)x)[p];
  unsigned int d[SLOTS];
#pragma unroll
  for (int s = 0; s < SLOTS; s++) d[s] = 0xFFFFFFFFu;
  unsigned int T = 0xFFFFFFFFu;
  unsigned int cnt = 0;
  for (int mm = 0; mm < QLEN / 4; mm++) {
    float4 c01 = ((const float4*)cand)[2 * mm];
    float4 c23 = ((const float4*)cand)[2 * mm + 1];
    unsigned int idx0 = (unsigned int)(c0 + 4 * mm);
    cand_step(me.x, me.y, c01.x, c01.y, idx0 + 0u, T, sbuf, t, cnt);
    cand_step(me.x, me.y, c01.z, c01.w, idx0 + 1u, T, sbuf, t, cnt);
    cand_step(me.x, me.y, c23.x, c23.y, idx0 + 2u, T, sbuf, t, cnt);
    cand_step(me.x, me.y, c23.z, c23.w, idx0 + 3u, T, sbuf, t, cnt);
    if (__any((int)(cnt >= 13u))) {
#pragma unroll
      for (int j = 0; j < 16; j++) {
        unsigned int u = ((unsigned)j < cnt) ? sbuf[j * 256 + t] : 0xFFFFFFFFu;
#pragma unroll
        for (int s = 0; s < SLOTS; s++) {
          unsigned int lo = min(u, d[s]);
          unsigned int hi = max(u, d[s]);
          d[s] = lo; u = hi;
        }
      }
      cnt = 0;
      T = d[SLOTS - 1];
    }
  }
  // final flush of residual buffer entries
#pragma unroll
  for (int j = 0; j < 16; j++) {
    unsigned int u = ((unsigned)j < cnt) ? sbuf[j * 256 + t] : 0xFFFFFFFFu;
#pragma unroll
    for (int s = 0; s < SLOTS; s++) {
      unsigned int lo = min(u, d[s]);
      unsigned int hi = max(u, d[s]);
      d[s] = lo; u = hi;
    }
  }
#pragma unroll
  for (int s = 0; s < SLOTS; s++)
    ipart[((size_t)(q * SLOTS + s)) * PTS + p] = d[s];
}

// ---------------------------------------------------------------------------
// Merge + geometry. Gathers 128 packed survivors -> packed top-8 -> exact
// (f32 ref key, idx) lex re-rank -> reference top-5 -> covariance ->
// ssteqr/SLAEV2 replica -> angle/axes + interleaved lcc (float2).
// Also writes the x-passthrough rows (0,1) of lftx and zero-fills the
// padding rows 66..79 (so the padded c1 GEMM never reads garbage).
// 256 blocks x 128 threads.
// ---------------------------------------------------------------------------
__global__ __launch_bounds__(128) void merge_geom(const float* __restrict__ x,
    const unsigned int* __restrict__ ipart,
    float2* __restrict__ lcct2,
    float* __restrict__ angle_out, float2* __restrict__ axes_out,
    float* __restrict__ lftx) {
  int p = blockIdx.x * 128 + threadIdx.x;
  int batch = p >> 12;
  const float2* xb = (const float2*)(x + (size_t)batch * NPTS * 2);
  float2 me = ((const float2*)x)[p];
  lftx[p] = me.x;
  lftx[PTS + p] = me.y;
#pragma unroll
  for (int r = 66; r < 80; r++) lftx[(size_t)r * PTS + p] = 0.0f;
  float sqn = ref_sq(me.x, me.y);

  unsigned int g[SLOTS];
#pragma unroll
  for (int s = 0; s < SLOTS; s++) g[s] = 0xFFFFFFFFu;
  for (int qs = 0; qs < QN * SLOTS; qs++) {
    unsigned int v = ipart[(size_t)qs * PTS + p];
#pragma unroll
    for (int s = 0; s < SLOTS; s++) {
      unsigned int lo = min(v, g[s]);
      unsigned int hi = max(v, g[s]);
      g[s] = lo; v = hi;
    }
  }
  float dk[5]; int id[5];
#pragma unroll
  for (int s = 0; s < 5; s++) { dk[s] = 3.0e38f; id[s] = 0x7fffffff; }
#pragma unroll
  for (int s8 = 0; s8 < SLOTS; s8++) {
    int ci = (int)(g[s8] & 0xFFFu);
    float2 c = xb[ci];
    float key = ref_key(me.x, me.y, sqn, c.x, c.y, ref_sq(c.x, c.y));
    float v = key; int vi = ci;
#pragma unroll
    for (int s = 0; s < 5; s++) {
      bool lt = (v < dk[s]) || (v == dk[s] && vi < id[s]);
      float tv = dk[s]; int ti = id[s];
      if (lt) { dk[s] = v; id[s] = vi; v = tv; vi = ti; }
    }
  }
  float rx[5], ry[5];
  float sx = 0.f, sy = 0.f;
#pragma unroll
  for (int k = 0; k < 5; k++) {
    float2 nb = xb[id[k]];
    rx[k] = frn_sub(nb.x, me.x); ry[k] = frn_sub(nb.y, me.y);
    sx = frn_add(sx, rx[k]); sy = frn_add(sy, ry[k]);
  }
  float mx = frn_div(sx, 5.0f), my = frn_div(sy, 5.0f);
  float c00 = 0.f, c01 = 0.f, c11 = 0.f;
#pragma unroll
  for (int k = 0; k < 5; k++) {
    rx[k] = frn_sub(rx[k], mx); ry[k] = frn_sub(ry[k], my);
    c00 = frn_add(c00, frn_mul(rx[k], rx[k]));
    c01 = frn_add(c01, frn_mul(rx[k], ry[k]));
    c11 = frn_add(c11, frn_mul(ry[k], ry[k]));
  }
  c00 = frn_div(c00, 4.0f); c01 = frn_div(c01, 4.0f); c11 = frn_div(c11, 4.0f);
  float A = frn_add(c00, 1e-6f), Bv = c01, C = frn_add(c11, 1e-6f);

  // ---- ssteqr 2x2 replica ----
  float absA = fabsf(A), absC = fabsf(C), absB = fabsf(Bv);
  float thr = frn_mul(frn_mul(sqrtf(absA), sqrtf(absC)), EPS_L);
  bool diag = (absB == 0.f) || (absB <= thr);
  if (!diag) {
    bool qr = (absC < absA);
    float b2 = frn_mul(absB, absB);
    float t = qr ? frn_add(frn_mul(frn_mul(EPS2_L, absC), absA), SAFMIN_L)
                 : frn_add(frn_mul(frn_mul(EPS2_L, absA), absC), SAFMIN_L);
    if (b2 <= t) diag = true;
  }
  float e1, e2, v00, v10, v01, v11;
  if (diag) {
    if (C < A) { e1 = C; e2 = A; v00 = 0.f; v10 = 1.f; v01 = 1.f; v11 = 0.f; }
    else       { e1 = A; e2 = C; v00 = 1.f; v10 = 0.f; v01 = 0.f; v11 = 1.f; }
  } else {
    // ---- SLAEV2 replica ----
    float sm = frn_add(A, C), df = frn_sub(A, C);
    float adf = fabsf(df), tb = frn_add(Bv, Bv), ab = fabsf(tb);
    float rt;
    if (adf > ab) {
      float r = frn_div(ab, adf);
      rt = frn_mul(adf, sqrtf(frn_add(1.0f, frn_mul(r, r))));
    } else if (adf < ab) {
      float r = frn_div(adf, ab);
      rt = frn_mul(ab, sqrtf(frn_add(1.0f, frn_mul(r, r))));
    } else {
      rt = frn_mul(ab, sqrtf(2.0f));
    }
    float acmx, acmn;
    if (absA > absC) { acmx = A; acmn = C; } else { acmx = C; acmn = A; }
    float rt1, rt2; int sgn1;
    if (sm < 0.f) {
      rt1 = frn_mul(0.5f, frn_sub(sm, rt)); sgn1 = -1;
      rt2 = frn_sub(frn_mul(frn_div(acmx, rt1), acmn), frn_mul(frn_div(Bv, rt1), Bv));
    } else if (sm > 0.f) {
      rt1 = frn_mul(0.5f, frn_add(sm, rt)); sgn1 = 1;
      rt2 = frn_sub(frn_mul(frn_div(acmx, rt1), acmn), frn_mul(frn_div(Bv, rt1), Bv));
    } else {
      rt1 = frn_mul(0.5f, rt); rt2 = frn_mul(-0.5f, rt); sgn1 = 1;
    }
    float cs, cs1, sn1; int sgn2;
    if (df >= 0.f) { cs = frn_add(df, rt); sgn2 = 1; }
    else           { cs = frn_sub(df, rt); sgn2 = -1; }
    float acs = fabsf(cs);
    if (acs > ab) {
      float ct = frn_div(-tb, cs);
      sn1 = frn_div(1.0f, sqrtf(frn_add(1.0f, frn_mul(ct, ct))));
      cs1 = frn_mul(ct, sn1);
    } else {
      if (ab == 0.f) { cs1 = 1.0f; sn1 = 0.0f; }
      else {
        float tn = frn_div(-cs, tb);
        cs1 = frn_div(1.0f, sqrtf(frn_add(1.0f, frn_mul(tn, tn))));
        sn1 = frn_mul(tn, cs1);
      }
    }
    if (sgn1 == sgn2) { float t = cs1; cs1 = -sn1; sn1 = t; }
    if (rt2 < rt1) { e1 = rt2; e2 = rt1; v00 = -sn1; v10 = cs1; v01 = cs1;  v11 = sn1; }
    else           { e1 = rt1; e2 = rt2; v00 = cs1;  v10 = sn1; v01 = -sn1; v11 = cs1; }
  }

  angle_out[p] = atan2f(v11, v01);
  float aM = sqrtf(fmaxf(e2, 1e-6f));
  float am = sqrtf(fmaxf(e1, 1e-6f));
  float den = frn_add(fmaxf(aM, am), 1e-6f);
  axes_out[p] = make_float2(fmaxf(frn_div(aM, den), 0.2f),
                            fmaxf(frn_div(am, den), 0.2f));

  size_t rowb = (size_t)p * 5;
#pragma unroll
  for (int k = 0; k < 5; k++) {
    float l0 = frn_add(frn_mul(rx[k], v00), frn_mul(ry[k], v10));
    float l1 = frn_add(frn_mul(rx[k], v01), frn_mul(ry[k], v11));
    lcct2[rowb + k] = make_float2(l0, l1);
  }
}

// ---------------------------------------------------------------------------
// Fused layer1+layer2: out[n][m] = relu(lb2[n] + sum_k relu(h1[k][m]) * w2..)
// where h1[k][m] = fmaf(l.y, lw1t[2k+1], fmaf(l.x, lw1t[2k], lb1[k])) is
// computed into the A-tile LDS from lcct2 (no h1 round-trip through HBM).
// MB=NB=128, KB=16, KTILES=4, Kstr(w)=64.
// ---------------------------------------------------------------------------
__global__ __launch_bounds__(256, 3) void gemm_l2(
    const float2* __restrict__ lcct2, const float* __restrict__ lw1t,
    const float* __restrict__ lb1,
    const float* __restrict__ wt, const float* __restrict__ bias,
    float* __restrict__ out_t, int M) {
  __shared__ float alds[16 * 128];
  __shared__ float wlds[16 * 128];
  __shared__ float w1s[192];  // [0..127]=lw1t (64 pairs), [128..191]=lb1
  int t = threadIdx.x;
  int m0 = blockIdx.x * 128;
  if (t < 192) w1s[t] = (t < 128) ? lw1t[t] : lb1[t - 128];
  int mloc = t & 127;
  int kbase = t >> 7;  // 0 or 1 (wave-uniform)
  float2 lme = lcct2[m0 + mloc];
  int tm = t & 15;
  int tn = t >> 4;
  float acc[8][8];
#pragma unroll
  for (int j = 0; j < 8; j++) {
    float b = bias[tn * 8 + j];
#pragma unroll
    for (int i = 0; i < 8; i++) acc[j][i] = b;
  }
  for (int kt = 0; kt < 4; kt++) {
    int k0 = kt * 16;
    __syncthreads();
    // A-stage: compute h1 tile in place of a global load.
#pragma unroll
    for (int pp = 0; pp < 8; pp++) {
      int kk = pp * 2 + kbase;
      int k = k0 + kk;
      float h = fmaf(lme.y, w1s[2 * k + 1], fmaf(lme.x, w1s[2 * k], w1s[128 + k]));
      alds[kk * 128 + mloc] = fmaxf(h, 0.f);
    }
    // W-stage (WPASS = 2, Kstr = 64)
#pragma unroll
    for (int pp = 0; pp < 2; pp++) {
      int e = pp * 256 + t;
      int n = e >> 2;
      int kc = e & 3;
      float4 v = *(const float4*)(wt + (size_t)n * 64 + k0 + kc * 4);
      wlds[(kc * 4 + 0) * 128 + n] = v.x;
      wlds[(kc * 4 + 1) * 128 + n] = v.y;
      wlds[(kc * 4 + 2) * 128 + n] = v.z;
      wlds[(kc * 4 + 3) * 128 + n] = v.w;
    }
    __syncthreads();
#pragma unroll
    for (int kk = 0; kk < 16; kk++) {
      float af[8], wf[8];
      *(float4*)(af)     = *(const float4*)(alds + kk * 128 + tm * 8);
      *(float4*)(af + 4) = *(const float4*)(alds + kk * 128 + tm * 8 + 4);
      *(float4*)(wf)     = *(const float4*)(wlds + kk * 128 + tn * 8);
      *(float4*)(wf + 4) = *(const float4*)(wlds + kk * 128 + tn * 8 + 4);
#pragma unroll
      for (int j = 0; j < 8; j++)
#pragma unroll
        for (int i = 0; i < 8; i++)
          acc[j][i] = fmaf(af[i], wf[j], acc[j][i]);
    }
  }
#pragma unroll
  for (int j = 0; j < 8; j++) {
    int n = tn * 8 + j;
    float4 o0, o1;
    o0.x = fmaxf(acc[j][0], 0.f); o0.y = fmaxf(acc[j][1], 0.f);
    o0.z = fmaxf(acc[j][2], 0.f); o0.w = fmaxf(acc[j][3], 0.f);
    o1.x = fmaxf(acc[j][4], 0.f); o1.y = fmaxf(acc[j][5], 0.f);
    o1.z = fmaxf(acc[j][6], 0.f); o1.w = fmaxf(acc[j][7], 0.f);
    float* dst = out_t + (size_t)n * M + m0 + tm * 8;
    *(float4*)(dst) = o0;
    *(float4*)(dst + 4) = o1;
  }
}

// ---------------------------------------------------------------------------
// Fused layer3 + maxpool: M-tile = 320 rows = 64 whole points (K=5), so the
// per-point max over 5 rows never crosses a block boundary. 512 threads:
// thread = (pt, ng) owns one point's 5 rows x 8 outputs (acc[5][8]).
// Ascending-k fmaf chain and relu->max tree replicate the unfused
// gemm_f32<256,64,8> + maxpack pair bit-exactly. h3 never touches HBM.
// Writes lftx rows 2..65 directly.
// ---------------------------------------------------------------------------
__global__ __launch_bounds__(512, 4) void gemm_l3max(
    const float* __restrict__ h2, const float* __restrict__ wt,
    const float* __restrict__ bias, float* __restrict__ lftx) {
  __shared__ float alds[16 * 320];  // 20 KB
  __shared__ float wlds[16 * 64];   // 4 KB
  int t = threadIdx.x;
  int m0 = blockIdx.x * 320;
  int pt = t & 63;
  int ng = t >> 6;  // 0..7 (wave-uniform)
  float acc[5][8];
#pragma unroll
  for (int j = 0; j < 8; j++) {
    float b = bias[ng * 8 + j];
#pragma unroll
    for (int r = 0; r < 5; r++) acc[r][j] = b;
  }
  for (int kt = 0; kt < 8; kt++) {
    int k0 = kt * 16;
    __syncthreads();
    // A stage: 16 k x 320 m = 1280 float4 (waves 0-3 do 3 passes, 4-7 do 2).
    for (int e = t; e < 1280; e += 512) {
      int kk = e / 80;
      int m4 = e - kk * 80;
      float4 v = *(const float4*)(h2 + (size_t)(k0 + kk) * ROWS + m0 + m4 * 4);
      *(float4*)(alds + kk * 320 + m4 * 4) = v;
    }
    // W stage: 16 k x 64 n = 256 float4 (threads 0..255), Kstr=128.
    if (t < 256) {
      int n = t >> 2, kc = t & 3;
      float4 v = *(const float4*)(wt + (size_t)n * 128 + k0 + kc * 4);
      wlds[(kc * 4 + 0) * 64 + n] = v.x;
      wlds[(kc * 4 + 1) * 64 + n] = v.y;
      wlds[(kc * 4 + 2) * 64 + n] = v.z;
      wlds[(kc * 4 + 3) * 64 + n] = v.w;
    }
    __syncthreads();
#pragma unroll
    for (int kk = 0; kk < 16; kk++) {
      float af[5], wf[8];
#pragma unroll
      for (int r = 0; r < 5; r++) af[r] = alds[kk * 320 + pt * 5 + r];
      *(float4*)(wf)     = *(const float4*)(wlds + kk * 64 + ng * 8);
      *(float4*)(wf + 4) = *(const float4*)(wlds + kk * 64 + ng * 8 + 4);
#pragma unroll
      for (int r = 0; r < 5; r++)
#pragma unroll
        for (int j = 0; j < 8; j++)
          acc[r][j] = fmaf(af[r], wf[j], acc[r][j]);
    }
  }
  int p = blockIdx.x * 64 + pt;
#pragma unroll
  for (int j = 0; j < 8; j++) {
    float r0 = fmaxf(acc[0][j], 0.f), r1 = fmaxf(acc[1][j], 0.f);
    float r2 = fmaxf(acc[2][j], 0.f), r3 = fmaxf(acc[3][j], 0.f);
    float r4 = fmaxf(acc[4][j], 0.f);
    float m = fmaxf(fmaxf(fmaxf(r0, r1), fmaxf(r2, r3)), r4);
    lftx[(size_t)(ng * 8 + j + 2) * PTS + p] = m;
  }
}

// ---------------------------------------------------------------------------
// Register-tiled fp32 GEMM: out[n][m] = relu(bias[n] + sum_k w[n][k]*in[k][m])
// ---------------------------------------------------------------------------
template <int MB, int NB, int KTILES>
__global__ __launch_bounds__(256, 3) void gemm_f32(
    const float* __restrict__ in_t, const float* __restrict__ wt,
    const float* __restrict__ bias, float* __restrict__ out_t,
    int M, int Kstr) {
  constexpr int KB = 16;
  __shared__ float alds[KB * MB];
  __shared__ float wlds[KB * NB];
  int t = threadIdx.x;
  int m0 = blockIdx.x * MB;
  constexpr int TM = MB / 8;
  constexpr int TMS = (MB == 128) ? 4 : 5;
  int tm = t & (TM - 1);
  int tn = t >> TMS;
  float acc[8][8];
#pragma unroll
  for (int j = 0; j < 8; j++) {
    float b = bias[tn * 8 + j];
#pragma unroll
    for (int i = 0; i < 8; i++) acc[j][i] = b;
  }
  for (int kt = 0; kt < KTILES; kt++) {
    int k0 = kt * KB;
    __syncthreads();
    constexpr int APASS = (KB * MB / 4) / 256;
#pragma unroll
    for (int pp = 0; pp < APASS; pp++) {
      int e = pp * 256 + t;
      int kk = e / (MB / 4);
      int m4 = e - kk * (MB / 4);
      float4 v = *(const float4*)(in_t + (size_t)(k0 + kk) * M + m0 + m4 * 4);
      *(float4*)(alds + kk * MB + m4 * 4) = v;
    }
    constexpr int WPASS = (KB * NB / 4) / 256;
#pragma unroll
    for (int pp = 0; pp < WPASS; pp++) {
      int e = pp * 256 + t;
      int n = e >> 2;
      int kc = e & 3;
      float4 v = *(const float4*)(wt + (size_t)n * Kstr + k0 + kc * 4);
      wlds[(kc * 4 + 0) * NB + n] = v.x;
      wlds[(kc * 4 + 1) * NB + n] = v.y;
      wlds[(kc * 4 + 2) * NB + n] = v.z;
      wlds[(kc * 4 + 3) * NB + n] = v.w;
    }
    __syncthreads();
#pragma unroll
    for (int kk = 0; kk < KB; kk++) {
      float af[8], wf[8];
      *(float4*)(af)     = *(const float4*)(alds + kk * MB + tm * 8);
      *(float4*)(af + 4) = *(const float4*)(alds + kk * MB + tm * 8 + 4);
      *(float4*)(wf)     = *(const float4*)(wlds + kk * NB + tn * 8);
      *(float4*)(wf + 4) = *(const float4*)(wlds + kk * NB + tn * 8 + 4);
#pragma unroll
      for (int j = 0; j < 8; j++)
#pragma unroll
        for (int i = 0; i < 8; i++)
          acc[j][i] = fmaf(af[i], wf[j], acc[j][i]);
    }
  }
#pragma unroll
  for (int j = 0; j < 8; j++) {
    int n = tn * 8 + j;
    float4 o0, o1;
    o0.x = fmaxf(acc[j][0], 0.f); o0.y = fmaxf(acc[j][1], 0.f);
    o0.z = fmaxf(acc[j][2], 0.f); o0.w = fmaxf(acc[j][3], 0.f);
    o1.x = fmaxf(acc[j][4], 0.f); o1.y = fmaxf(acc[j][5], 0.f);
    o1.z = fmaxf(acc[j][6], 0.f); o1.w = fmaxf(acc[j][7], 0.f);
    float* dst = out_t + (size_t)n * M + m0 + tm * 8;
    *(float4*)(dst) = o0;
    *(float4*)(dst + 4) = o1;
  }
}

// ---------------------------------------------------------------------------
// Head layer 2 GEMM with direct row-major store: out[p*128 + n] (d_out
// layout), eliminating the transpose pass. Same fmaf accumulation as
// gemm_f32<128,128,8>; only the store addressing changes. Per wave per row
// the 64 lanes cover 16 rows x 128 contiguous bytes -> fully coalesced.
// MB=NB=128, KB=16, KTILES=8, M=PTS, Kstr=128.
// ---------------------------------------------------------------------------
__global__ __launch_bounds__(256, 3) void gemm_out(
    const float* __restrict__ in_t, const float* __restrict__ wt,
    const float* __restrict__ bias, float* __restrict__ out) {
  __shared__ float alds[16 * 128];
  __shared__ float wlds[16 * 128];
  int t = threadIdx.x;
  int m0 = blockIdx.x * 128;
  int tm = t & 15;
  int tn = t >> 4;
  float acc[8][8];
#pragma unroll
  for (int j = 0; j < 8; j++) {
    float b = bias[tn * 8 + j];
#pragma unroll
    for (int i = 0; i < 8; i++) acc[j][i] = b;
  }
  for (int kt = 0; kt < 8; kt++) {
    int k0 = kt * 16;
    __syncthreads();
#pragma unroll
    for (int pp = 0; pp < 2; pp++) {
      int e = pp * 256 + t;
      int kk = e >> 5;
      int m4 = e & 31;
      float4 v = *(const float4*)(in_t + (size_t)(k0 + kk) * PTS + m0 + m4 * 4);
      *(float4*)(alds + kk * 128 + m4 * 4) = v;
    }
#pragma unroll
    for (int pp = 0; pp < 2; pp++) {
      int e = pp * 256 + t;
      int n = e >> 2;
      int kc = e & 3;
      float4 v = *(const float4*)(wt + (size_t)n * 128 + k0 + kc * 4);
      wlds[(kc * 4 + 0) * 128 + n] = v.x;
      wlds[(kc * 4 + 1) * 128 + n] = v.y;
      wlds[(kc * 4 + 2) * 128 + n] = v.z;
      wlds[(kc * 4 + 3) * 128 + n] = v.w;
    }
    __syncthreads();
#pragma unroll
    for (int kk = 0; kk < 16; kk++) {
      float af[8], wf[8];
      *(float4*)(af)     = *(const float4*)(alds + kk * 128 + tm * 8);
      *(float4*)(af + 4) = *(const float4*)(alds + kk * 128 + tm * 8 + 4);
      *(float4*)(wf)     = *(const float4*)(wlds + kk * 128 + tn * 8);
      *(float4*)(wf + 4) = *(const float4*)(wlds + kk * 128 + tn * 8 + 4);
#pragma unroll
      for (int j = 0; j < 8; j++)
#pragma unroll
        for (int i = 0; i < 8; i++)
          acc[j][i] = fmaf(af[i], wf[j], acc[j][i]);
    }
  }
  // Transposed (row-major) epilogue: 8 rows x 2 float4 per thread.
#pragma unroll
  for (int i = 0; i < 8; i++) {
    int m = m0 + tm * 8 + i;
    float4 o0, o1;
    o0.x = fmaxf(acc[0][i], 0.f); o0.y = fmaxf(acc[1][i], 0.f);
    o0.z = fmaxf(acc[2][i], 0.f); o0.w = fmaxf(acc[3][i], 0.f);
    o1.x = fmaxf(acc[4][i], 0.f); o1.y = fmaxf(acc[5][i], 0.f);
    o1.z = fmaxf(acc[6][i], 0.f); o1.w = fmaxf(acc[7][i], 0.f);
    float* dst = out + (size_t)m * 128 + tn * 8;
    *(float4*)(dst) = o0;
    *(float4*)(dst + 4) = o1;
  }
}

// ---------------------------------------------------------------------------
extern "C" void kernel_launch(void* const* d_in, const int* in_sizes, int n_in,
                              void* d_out, int out_size, void* d_ws, size_t ws_size,
                              hipStream_t stream) {
  const float* x   = (const float*)d_in[0];
  const float* lb1 = (const float*)d_in[2];
  const float* lb2 = (const float*)d_in[4];
  const float* lb3 = (const float*)d_in[6];
  const float* cb1 = (const float*)d_in[8];
  const float* cb2 = (const float*)d_in[10];
  const float* tb1 = (const float*)d_in[12];
  const float* tb2 = (const float*)d_in[14];

  float* out = (float*)d_out;
  float* angle_out = out + 8388608;
  float* axes_out  = out + 8421376;

  // Workspace (floats), lifetime-overlapped:
  //   wt    [67712]
  //   R1    [10485760]  ipart (knn->merge, 4M u32)
  //   R2    [10485760]  a1 (c1->c2, t1->t2)
  //   R3    [20971520]  h2 (l2->l3max)
  //   lftx  [2621440]
  //   lcct2 [327680]    interleaved (l0,l1) per row
  float* W = (float*)d_ws;
  float* wt    = W;
  float* R1    = W + 67712;
  float* R2    = R1 + 10485760;
  float* R3    = R2 + 10485760;
  float* lftx  = R3 + 20971520;
  float* lcct2 = lftx + 2621440;
  unsigned int* ipart = (unsigned int*)R1;
  float* a1    = R2;
  float* h2    = R3;

  prep_w<<<7, 256, 0, stream>>>((const float*)d_in[1], (const float*)d_in[3], (const float*)d_in[5],
                                (const float*)d_in[7], (const float*)d_in[9],
                                (const float*)d_in[11], (const float*)d_in[13], wt);
  knn_scan<<<2048, 256, 0, stream>>>(x, ipart);
  merge_geom<<<256, 128, 0, stream>>>(x, ipart, (float2*)lcct2, angle_out, (float2*)axes_out, lftx);

  gemm_l2<<<ROWS / 128, 256, 0, stream>>>((const float2*)lcct2, wt + 0, lb1,
                                          wt + 128, lb2, h2, ROWS);
  gemm_l3max<<<PTS / 64, 512, 0, stream>>>(h2, wt + 8320, lb3, lftx);

  gemm_f32<128, 128, 5><<<PTS / 128, 256, 0, stream>>>(lftx, wt + 16512, cb1, a1, PTS, 80);
  gemm_out<<<PTS / 128, 256, 0, stream>>>(a1, wt + 26752, cb2, out);
  gemm_f32<128, 128, 4><<<PTS / 128, 256, 0, stream>>>(lftx + 2 * PTS, wt + 43136, tb1, a1, PTS, 64);
  gemm_out<<<PTS / 128, 256, 0, stream>>>(a1, wt + 51328, tb2, out + 4194304);
}

// Round 4
// 306.107 us; speedup vs baseline: 1.2638x; 1.1447x over previous
//
#include <hip/hip_runtime.h>
#include <math.h>

#pragma clang fp contract(off)

#define NPTS 4096
#define PTS  32768
#define ROWS 163840   // PTS * 5
#define QN   8        // candidate slices per batch
#define QLEN 512      // NPTS / QN
#define SLOTS 8       // packed top-k slots per slice (and global survivors)

// LAPACK single-precision machine constants (gfortran/IEEE):
#define EPS_L   5.9604644775390625e-8f    // 2^-24  SLAMCH('E')
#define EPS2_L  3.5527136788005009e-15f   // 2^-48
#define SAFMIN_L 1.1754943508222875e-38f  // 2^-126

// Round-to-nearest, non-contractible f32 ops (file pragma disables fusion).
__device__ __forceinline__ float frn_mul(float a, float b) { float r = a * b; return r; }
__device__ __forceinline__ float frn_add(float a, float b) { float r = a + b; return r; }
__device__ __forceinline__ float frn_sub(float a, float b) { float r = a - b; return r; }
__device__ __forceinline__ float frn_div(float a, float b) { float r = a / b; return r; }

__device__ __forceinline__ float ref_sq(float x0, float x1) {
  return frn_add(frn_mul(x0, x0), frn_mul(x1, x1));
}
// dist_sq[n,m] = fl( fl(sq_n + sq_m) - 2*dot ), dot = fma(ny*my, fl(nx*mx)).
__device__ __forceinline__ float ref_key(float nx, float ny, float sqn,
                                         float mx, float my, float sqm) {
  float dot = fmaf(ny, my, frn_mul(nx, mx));
  float s = frn_add(sqn, sqm);
  return fmaf(-2.0f, dot, s);
}

// ---------------------------------------------------------------------------
// Weight transpose prep, zero-padded K stride: wt[j*Kp + i] = (i<K)? w[i*N+j]:0
// ---------------------------------------------------------------------------
__global__ __launch_bounds__(256) void prep_w(
    const float* __restrict__ lw1, const float* __restrict__ lw2, const float* __restrict__ lw3,
    const float* __restrict__ cw1, const float* __restrict__ cw2,
    const float* __restrict__ tw1, const float* __restrict__ tw2,
    float* __restrict__ wt) {
  const int Ks[7]   = {2, 64, 128, 66, 128, 64, 128};
  const int Kp[7]   = {2, 64, 128, 80, 128, 64, 128};
  const int Ns[7]   = {64, 128, 64, 128, 128, 128, 128};
  const int offs[7] = {0, 128, 8320, 16512, 26752, 43136, 51328};
  const float* srcs[7] = {lw1, lw2, lw3, cw1, cw2, tw1, tw2};
  int b = blockIdx.x;
  const float* src = srcs[b];
  float* dst = wt + offs[b];
  int K = Ks[b], KP = Kp[b], N = Ns[b];
  for (int e = threadIdx.x; e < KP * N; e += 256) {
    int j = e / KP, i = e - j * KP;
    dst[e] = (i < K) ? src[i * N + j] : 0.0f;
  }
}

// ---------------------------------------------------------------------------
// kNN scan: 1024 blocks = 128 point-groups x 8 candidate-slices of 512.
// QN=8 rebalance: flush count grows only ~log(QLEN) while threads/point
// halves -> ~15% less total lane-work than QN=16, same occupancy (4
// blocks/CU, 20 KB LDS). Threshold-filtered top-8, unroll-4, unconditional
// buffered append (failing write lands in slot cnt; only promoted when a
// passing value overwrites it). Flush-check every 4 candidates, cnt>=13
// (start-of-group cnt<=12, +4 appends -> slots <= 15 < 16).
// Packed value = (bits(dist)&0xFFFFF000)|idx (dist >= 0 u32-monotone).
// Monotone threshold T => no true top-8 element dropped (values distinct by
// idx); exact ref-key re-rank happens in merge_geom.
// ---------------------------------------------------------------------------
__device__ __forceinline__ void cand_step(float mex, float mey, float cx, float cy,
                                          unsigned int idx, unsigned int T,
                                          unsigned int* sbuf, int t,
                                          unsigned int& cnt) {
  float dx = mex - cx, dy = mey - cy;
  float dist = fmaf(dy, dy, dx * dx);
  unsigned int v = (__float_as_uint(dist) & 0xFFFFF000u) | idx;
  sbuf[cnt * 256 + t] = v;
  cnt += (v < T) ? 1u : 0u;
}

__global__ __launch_bounds__(256) void knn_scan(const float* __restrict__ x,
                                                unsigned int* __restrict__ ipart) {
  __shared__ float2 cand[QLEN];            // 4 KB
  __shared__ unsigned int sbuf[16 * 256];  // 16 KB survivor buffer
  int bx = blockIdx.x;
  int q = bx & (QN - 1);
  int pg = bx >> 3;
  int batch = pg >> 4;
  const float* xb = x + (size_t)batch * NPTS * 2;
  int c0 = q * QLEN;
  for (int i = threadIdx.x; i < QLEN; i += 256)
    cand[i] = ((const float2*)xb)[c0 + i];
  __syncthreads();
  int t = threadIdx.x;
  int p = pg * 256 + t;
  float2 me = ((const float2*)x)[p];
  unsigned int d[SLOTS];
#pragma unroll
  for (int s = 0; s < SLOTS; s++) d[s] = 0xFFFFFFFFu;
  unsigned int T = 0xFFFFFFFFu;
  unsigned int cnt = 0;
  for (int mm = 0; mm < QLEN / 4; mm++) {
    float4 c01 = ((const float4*)cand)[2 * mm];
    float4 c23 = ((const float4*)cand)[2 * mm + 1];
    unsigned int idx0 = (unsigned int)(c0 + 4 * mm);
    cand_step(me.x, me.y, c01.x, c01.y, idx0 + 0u, T, sbuf, t, cnt);
    cand_step(me.x, me.y, c01.z, c01.w, idx0 + 1u, T, sbuf, t, cnt);
    cand_step(me.x, me.y, c23.x, c23.y, idx0 + 2u, T, sbuf, t, cnt);
    cand_step(me.x, me.y, c23.z, c23.w, idx0 + 3u, T, sbuf, t, cnt);
    if (__any((int)(cnt >= 13u))) {
#pragma unroll
      for (int j = 0; j < 16; j++) {
        unsigned int u = ((unsigned)j < cnt) ? sbuf[j * 256 + t] : 0xFFFFFFFFu;
#pragma unroll
        for (int s = 0; s < SLOTS; s++) {
          unsigned int lo = min(u, d[s]);
          unsigned int hi = max(u, d[s]);
          d[s] = lo; u = hi;
        }
      }
      cnt = 0;
      T = d[SLOTS - 1];
    }
  }
  // final flush of residual buffer entries
#pragma unroll
  for (int j = 0; j < 16; j++) {
    unsigned int u = ((unsigned)j < cnt) ? sbuf[j * 256 + t] : 0xFFFFFFFFu;
#pragma unroll
    for (int s = 0; s < SLOTS; s++) {
      unsigned int lo = min(u, d[s]);
      unsigned int hi = max(u, d[s]);
      d[s] = lo; u = hi;
    }
  }
#pragma unroll
  for (int s = 0; s < SLOTS; s++)
    ipart[((size_t)(q * SLOTS + s)) * PTS + p] = d[s];
}

// ---------------------------------------------------------------------------
// Merge + geometry. Gathers QN*8=64 packed survivors -> packed top-8 ->
// exact (f32 ref key, idx) lex re-rank -> reference top-5 -> covariance ->
// ssteqr/SLAEV2 replica -> angle/axes + interleaved lcc (float2).
// Also writes the x-passthrough rows (0,1) of lftx and zero-fills the
// padding rows 66..79 (so the padded c1 GEMM never reads garbage).
// 256 blocks x 128 threads.
// ---------------------------------------------------------------------------
__global__ __launch_bounds__(128) void merge_geom(const float* __restrict__ x,
    const unsigned int* __restrict__ ipart,
    float2* __restrict__ lcct2,
    float* __restrict__ angle_out, float2* __restrict__ axes_out,
    float* __restrict__ lftx) {
  int p = blockIdx.x * 128 + threadIdx.x;
  int batch = p >> 12;
  const float2* xb = (const float2*)(x + (size_t)batch * NPTS * 2);
  float2 me = ((const float2*)x)[p];
  lftx[p] = me.x;
  lftx[PTS + p] = me.y;
#pragma unroll
  for (int r = 66; r < 80; r++) lftx[(size_t)r * PTS + p] = 0.0f;
  float sqn = ref_sq(me.x, me.y);

  unsigned int g[SLOTS];
#pragma unroll
  for (int s = 0; s < SLOTS; s++) g[s] = 0xFFFFFFFFu;
  for (int qs = 0; qs < QN * SLOTS; qs++) {
    unsigned int v = ipart[(size_t)qs * PTS + p];
#pragma unroll
    for (int s = 0; s < SLOTS; s++) {
      unsigned int lo = min(v, g[s]);
      unsigned int hi = max(v, g[s]);
      g[s] = lo; v = hi;
    }
  }
  float dk[5]; int id[5];
#pragma unroll
  for (int s = 0; s < 5; s++) { dk[s] = 3.0e38f; id[s] = 0x7fffffff; }
#pragma unroll
  for (int s8 = 0; s8 < SLOTS; s8++) {
    int ci = (int)(g[s8] & 0xFFFu);
    float2 c = xb[ci];
    float key = ref_key(me.x, me.y, sqn, c.x, c.y, ref_sq(c.x, c.y));
    float v = key; int vi = ci;
#pragma unroll
    for (int s = 0; s < 5; s++) {
      bool lt = (v < dk[s]) || (v == dk[s] && vi < id[s]);
      float tv = dk[s]; int ti = id[s];
      if (lt) { dk[s] = v; id[s] = vi; v = tv; vi = ti; }
    }
  }
  float rx[5], ry[5];
  float sx = 0.f, sy = 0.f;
#pragma unroll
  for (int k = 0; k < 5; k++) {
    float2 nb = xb[id[k]];
    rx[k] = frn_sub(nb.x, me.x); ry[k] = frn_sub(nb.y, me.y);
    sx = frn_add(sx, rx[k]); sy = frn_add(sy, ry[k]);
  }
  float mx = frn_div(sx, 5.0f), my = frn_div(sy, 5.0f);
  float c00 = 0.f, c01 = 0.f, c11 = 0.f;
#pragma unroll
  for (int k = 0; k < 5; k++) {
    rx[k] = frn_sub(rx[k], mx); ry[k] = frn_sub(ry[k], my);
    c00 = frn_add(c00, frn_mul(rx[k], rx[k]));
    c01 = frn_add(c01, frn_mul(rx[k], ry[k]));
    c11 = frn_add(c11, frn_mul(ry[k], ry[k]));
  }
  c00 = frn_div(c00, 4.0f); c01 = frn_div(c01, 4.0f); c11 = frn_div(c11, 4.0f);
  float A = frn_add(c00, 1e-6f), Bv = c01, C = frn_add(c11, 1e-6f);

  // ---- ssteqr 2x2 replica ----
  float absA = fabsf(A), absC = fabsf(C), absB = fabsf(Bv);
  float thr = frn_mul(frn_mul(sqrtf(absA), sqrtf(absC)), EPS_L);
  bool diag = (absB == 0.f) || (absB <= thr);
  if (!diag) {
    bool qr = (absC < absA);
    float b2 = frn_mul(absB, absB);
    float t = qr ? frn_add(frn_mul(frn_mul(EPS2_L, absC), absA), SAFMIN_L)
                 : frn_add(frn_mul(frn_mul(EPS2_L, absA), absC), SAFMIN_L);
    if (b2 <= t) diag = true;
  }
  float e1, e2, v00, v10, v01, v11;
  if (diag) {
    if (C < A) { e1 = C; e2 = A; v00 = 0.f; v10 = 1.f; v01 = 1.f; v11 = 0.f; }
    else       { e1 = A; e2 = C; v00 = 1.f; v10 = 0.f; v01 = 0.f; v11 = 1.f; }
  } else {
    // ---- SLAEV2 replica ----
    float sm = frn_add(A, C), df = frn_sub(A, C);
    float adf = fabsf(df), tb = frn_add(Bv, Bv), ab = fabsf(tb);
    float rt;
    if (adf > ab) {
      float r = frn_div(ab, adf);
      rt = frn_mul(adf, sqrtf(frn_add(1.0f, frn_mul(r, r))));
    } else if (adf < ab) {
      float r = frn_div(adf, ab);
      rt = frn_mul(ab, sqrtf(frn_add(1.0f, frn_mul(r, r))));
    } else {
      rt = frn_mul(ab, sqrtf(2.0f));
    }
    float acmx, acmn;
    if (absA > absC) { acmx = A; acmn = C; } else { acmx = C; acmn = A; }
    float rt1, rt2; int sgn1;
    if (sm < 0.f) {
      rt1 = frn_mul(0.5f, frn_sub(sm, rt)); sgn1 = -1;
      rt2 = frn_sub(frn_mul(frn_div(acmx, rt1), acmn), frn_mul(frn_div(Bv, rt1), Bv));
    } else if (sm > 0.f) {
      rt1 = frn_mul(0.5f, frn_add(sm, rt)); sgn1 = 1;
      rt2 = frn_sub(frn_mul(frn_div(acmx, rt1), acmn), frn_mul(frn_div(Bv, rt1), Bv));
    } else {
      rt1 = frn_mul(0.5f, rt); rt2 = frn_mul(-0.5f, rt); sgn1 = 1;
    }
    float cs, cs1, sn1; int sgn2;
    if (df >= 0.f) { cs = frn_add(df, rt); sgn2 = 1; }
    else           { cs = frn_sub(df, rt); sgn2 = -1; }
    float acs = fabsf(cs);
    if (acs > ab) {
      float ct = frn_div(-tb, cs);
      sn1 = frn_div(1.0f, sqrtf(frn_add(1.0f, frn_mul(ct, ct))));
      cs1 = frn_mul(ct, sn1);
    } else {
      if (ab == 0.f) { cs1 = 1.0f; sn1 = 0.0f; }
      else {
        float tn = frn_div(-cs, tb);
        cs1 = frn_div(1.0f, sqrtf(frn_add(1.0f, frn_mul(tn, tn))));
        sn1 = frn_mul(tn, cs1);
      }
    }
    if (sgn1 == sgn2) { float t = cs1; cs1 = -sn1; sn1 = t; }
    if (rt2 < rt1) { e1 = rt2; e2 = rt1; v00 = -sn1; v10 = cs1; v01 = cs1;  v11 = sn1; }
    else           { e1 = rt1; e2 = rt2; v00 = cs1;  v10 = sn1; v01 = -sn1; v11 = cs1; }
  }

  angle_out[p] = atan2f(v11, v01);
  float aM = sqrtf(fmaxf(e2, 1e-6f));
  float am = sqrtf(fmaxf(e1, 1e-6f));
  float den = frn_add(fmaxf(aM, am), 1e-6f);
  axes_out[p] = make_float2(fmaxf(frn_div(aM, den), 0.2f),
                            fmaxf(frn_div(am, den), 0.2f));

  size_t rowb = (size_t)p * 5;
#pragma unroll
  for (int k = 0; k < 5; k++) {
    float l0 = frn_add(frn_mul(rx[k], v00), frn_mul(ry[k], v10));
    float l1 = frn_add(frn_mul(rx[k], v01), frn_mul(ry[k], v11));
    lcct2[rowb + k] = make_float2(l0, l1);
  }
}

// ---------------------------------------------------------------------------
// Fused layer1+layer2: out[n][m] = relu(lb2[n] + sum_k relu(h1[k][m]) * w2..)
// where h1[k][m] = fmaf(l.y, lw1t[2k+1], fmaf(l.x, lw1t[2k], lb1[k])) is
// computed into the A-tile LDS from lcct2 (no h1 round-trip through HBM).
// MB=NB=128, KB=16, KTILES=4, Kstr(w)=64.
// ---------------------------------------------------------------------------
__global__ __launch_bounds__(256, 3) void gemm_l2(
    const float2* __restrict__ lcct2, const float* __restrict__ lw1t,
    const float* __restrict__ lb1,
    const float* __restrict__ wt, const float* __restrict__ bias,
    float* __restrict__ out_t, int M) {
  __shared__ float alds[16 * 128];
  __shared__ float wlds[16 * 128];
  __shared__ float w1s[192];  // [0..127]=lw1t (64 pairs), [128..191]=lb1
  int t = threadIdx.x;
  int m0 = blockIdx.x * 128;
  if (t < 192) w1s[t] = (t < 128) ? lw1t[t] : lb1[t - 128];
  int mloc = t & 127;
  int kbase = t >> 7;  // 0 or 1 (wave-uniform)
  float2 lme = lcct2[m0 + mloc];
  int tm = t & 15;
  int tn = t >> 4;
  float acc[8][8];
#pragma unroll
  for (int j = 0; j < 8; j++) {
    float b = bias[tn * 8 + j];
#pragma unroll
    for (int i = 0; i < 8; i++) acc[j][i] = b;
  }
  for (int kt = 0; kt < 4; kt++) {
    int k0 = kt * 16;
    __syncthreads();
    // A-stage: compute h1 tile in place of a global load.
#pragma unroll
    for (int pp = 0; pp < 8; pp++) {
      int kk = pp * 2 + kbase;
      int k = k0 + kk;
      float h = fmaf(lme.y, w1s[2 * k + 1], fmaf(lme.x, w1s[2 * k], w1s[128 + k]));
      alds[kk * 128 + mloc] = fmaxf(h, 0.f);
    }
    // W-stage (WPASS = 2, Kstr = 64)
#pragma unroll
    for (int pp = 0; pp < 2; pp++) {
      int e = pp * 256 + t;
      int n = e >> 2;
      int kc = e & 3;
      float4 v = *(const float4*)(wt + (size_t)n * 64 + k0 + kc * 4);
      wlds[(kc * 4 + 0) * 128 + n] = v.x;
      wlds[(kc * 4 + 1) * 128 + n] = v.y;
      wlds[(kc * 4 + 2) * 128 + n] = v.z;
      wlds[(kc * 4 + 3) * 128 + n] = v.w;
    }
    __syncthreads();
#pragma unroll
    for (int kk = 0; kk < 16; kk++) {
      float af[8], wf[8];
      *(float4*)(af)     = *(const float4*)(alds + kk * 128 + tm * 8);
      *(float4*)(af + 4) = *(const float4*)(alds + kk * 128 + tm * 8 + 4);
      *(float4*)(wf)     = *(const float4*)(wlds + kk * 128 + tn * 8);
      *(float4*)(wf + 4) = *(const float4*)(wlds + kk * 128 + tn * 8 + 4);
#pragma unroll
      for (int j = 0; j < 8; j++)
#pragma unroll
        for (int i = 0; i < 8; i++)
          acc[j][i] = fmaf(af[i], wf[j], acc[j][i]);
    }
  }
#pragma unroll
  for (int j = 0; j < 8; j++) {
    int n = tn * 8 + j;
    float4 o0, o1;
    o0.x = fmaxf(acc[j][0], 0.f); o0.y = fmaxf(acc[j][1], 0.f);
    o0.z = fmaxf(acc[j][2], 0.f); o0.w = fmaxf(acc[j][3], 0.f);
    o1.x = fmaxf(acc[j][4], 0.f); o1.y = fmaxf(acc[j][5], 0.f);
    o1.z = fmaxf(acc[j][6], 0.f); o1.w = fmaxf(acc[j][7], 0.f);
    float* dst = out_t + (size_t)n * M + m0 + tm * 8;
    *(float4*)(dst) = o0;
    *(float4*)(dst + 4) = o1;
  }
}

// ---------------------------------------------------------------------------
// Fused layer3 + maxpool: M-tile = 320 rows = 64 whole points (K=5), so the
// per-point max over 5 rows never crosses a block boundary. 512 threads:
// thread = (pt, ng) owns one point's 5 rows x 8 outputs (acc[5][8]).
// Ascending-k fmaf chain and relu->max tree replicate the unfused
// gemm_f32<256,64,8> + maxpack pair bit-exactly. h3 never touches HBM.
// Writes lftx rows 2..65 directly.
// ---------------------------------------------------------------------------
__global__ __launch_bounds__(512, 4) void gemm_l3max(
    const float* __restrict__ h2, const float* __restrict__ wt,
    const float* __restrict__ bias, float* __restrict__ lftx) {
  __shared__ float alds[16 * 320];  // 20 KB
  __shared__ float wlds[16 * 64];   // 4 KB
  int t = threadIdx.x;
  int m0 = blockIdx.x * 320;
  int pt = t & 63;
  int ng = t >> 6;  // 0..7 (wave-uniform)
  float acc[5][8];
#pragma unroll
  for (int j = 0; j < 8; j++) {
    float b = bias[ng * 8 + j];
#pragma unroll
    for (int r = 0; r < 5; r++) acc[r][j] = b;
  }
  for (int kt = 0; kt < 8; kt++) {
    int k0 = kt * 16;
    __syncthreads();
    // A stage: 16 k x 320 m = 1280 float4 (waves 0-3 do 3 passes, 4-7 do 2).
    for (int e = t; e < 1280; e += 512) {
      int kk = e / 80;
      int m4 = e - kk * 80;
      float4 v = *(const float4*)(h2 + (size_t)(k0 + kk) * ROWS + m0 + m4 * 4);
      *(float4*)(alds + kk * 320 + m4 * 4) = v;
    }
    // W stage: 16 k x 64 n = 256 float4 (threads 0..255), Kstr=128.
    if (t < 256) {
      int n = t >> 2, kc = t & 3;
      float4 v = *(const float4*)(wt + (size_t)n * 128 + k0 + kc * 4);
      wlds[(kc * 4 + 0) * 64 + n] = v.x;
      wlds[(kc * 4 + 1) * 64 + n] = v.y;
      wlds[(kc * 4 + 2) * 64 + n] = v.z;
      wlds[(kc * 4 + 3) * 64 + n] = v.w;
    }
    __syncthreads();
#pragma unroll
    for (int kk = 0; kk < 16; kk++) {
      float af[5], wf[8];
#pragma unroll
      for (int r = 0; r < 5; r++) af[r] = alds[kk * 320 + pt * 5 + r];
      *(float4*)(wf)     = *(const float4*)(wlds + kk * 64 + ng * 8);
      *(float4*)(wf + 4) = *(const float4*)(wlds + kk * 64 + ng * 8 + 4);
#pragma unroll
      for (int r = 0; r < 5; r++)
#pragma unroll
        for (int j = 0; j < 8; j++)
          acc[r][j] = fmaf(af[r], wf[j], acc[r][j]);
    }
  }
  int p = blockIdx.x * 64 + pt;
#pragma unroll
  for (int j = 0; j < 8; j++) {
    float r0 = fmaxf(acc[0][j], 0.f), r1 = fmaxf(acc[1][j], 0.f);
    float r2 = fmaxf(acc[2][j], 0.f), r3 = fmaxf(acc[3][j], 0.f);
    float r4 = fmaxf(acc[4][j], 0.f);
    float m = fmaxf(fmaxf(fmaxf(r0, r1), fmaxf(r2, r3)), r4);
    lftx[(size_t)(ng * 8 + j + 2) * PTS + p] = m;
  }
}

// ---------------------------------------------------------------------------
// Fused head layer 1: 512 blocks. bid<256 -> c1 tile (K=80, lftx rows 0..79),
// else t1 tile (K=64, lftx rows 2..65). Block-uniform branch; identical inner
// loop and fmaf order as the former separate gemm_f32 dispatches (bit-exact).
// Doubles blocks/CU (1 -> 2) for the latency-bound head phase.
// ---------------------------------------------------------------------------
__global__ __launch_bounds__(256, 3) void gemm_head1(
    const float* __restrict__ lftx, const float* __restrict__ wtbase,
    const float* __restrict__ cb1, const float* __restrict__ tb1,
    float* __restrict__ a1c, float* __restrict__ a1t) {
  __shared__ float alds[16 * 128];
  __shared__ float wlds[16 * 128];
  int bid = blockIdx.x;
  bool isC = bid < 256;
  const float* in_t = isC ? lftx : (lftx + 2 * PTS);
  const float* wt   = isC ? (wtbase + 16512) : (wtbase + 43136);
  const float* bias = isC ? cb1 : tb1;
  float* out_t      = isC ? a1c : a1t;
  int Kstr = isC ? 80 : 64;
  int KT   = isC ? 5 : 4;
  int m0 = (bid & 255) * 128;
  int t = threadIdx.x;
  int tm = t & 15;
  int tn = t >> 4;
  float acc[8][8];
#pragma unroll
  for (int j = 0; j < 8; j++) {
    float b = bias[tn * 8 + j];
#pragma unroll
    for (int i = 0; i < 8; i++) acc[j][i] = b;
  }
  for (int kt = 0; kt < KT; kt++) {
    int k0 = kt * 16;
    __syncthreads();
#pragma unroll
    for (int pp = 0; pp < 2; pp++) {
      int e = pp * 256 + t;
      int kk = e >> 5;
      int m4 = e & 31;
      float4 v = *(const float4*)(in_t + (size_t)(k0 + kk) * PTS + m0 + m4 * 4);
      *(float4*)(alds + kk * 128 + m4 * 4) = v;
    }
#pragma unroll
    for (int pp = 0; pp < 2; pp++) {
      int e = pp * 256 + t;
      int n = e >> 2;
      int kc = e & 3;
      float4 v = *(const float4*)(wt + (size_t)n * Kstr + k0 + kc * 4);
      wlds[(kc * 4 + 0) * 128 + n] = v.x;
      wlds[(kc * 4 + 1) * 128 + n] = v.y;
      wlds[(kc * 4 + 2) * 128 + n] = v.z;
      wlds[(kc * 4 + 3) * 128 + n] = v.w;
    }
    __syncthreads();
#pragma unroll
    for (int kk = 0; kk < 16; kk++) {
      float af[8], wf[8];
      *(float4*)(af)     = *(const float4*)(alds + kk * 128 + tm * 8);
      *(float4*)(af + 4) = *(const float4*)(alds + kk * 128 + tm * 8 + 4);
      *(float4*)(wf)     = *(const float4*)(wlds + kk * 128 + tn * 8);
      *(float4*)(wf + 4) = *(const float4*)(wlds + kk * 128 + tn * 8 + 4);
#pragma unroll
      for (int j = 0; j < 8; j++)
#pragma unroll
        for (int i = 0; i < 8; i++)
          acc[j][i] = fmaf(af[i], wf[j], acc[j][i]);
    }
  }
#pragma unroll
  for (int j = 0; j < 8; j++) {
    int n = tn * 8 + j;
    float4 o0, o1;
    o0.x = fmaxf(acc[j][0], 0.f); o0.y = fmaxf(acc[j][1], 0.f);
    o0.z = fmaxf(acc[j][2], 0.f); o0.w = fmaxf(acc[j][3], 0.f);
    o1.x = fmaxf(acc[j][4], 0.f); o1.y = fmaxf(acc[j][5], 0.f);
    o1.z = fmaxf(acc[j][6], 0.f); o1.w = fmaxf(acc[j][7], 0.f);
    float* dst = out_t + (size_t)n * PTS + m0 + tm * 8;
    *(float4*)(dst) = o0;
    *(float4*)(dst + 4) = o1;
  }
}

// ---------------------------------------------------------------------------
// Fused head layer 2 with direct row-major store into d_out. 512 blocks:
// bid<256 -> c2 (cls output), else t2 (topo output, d_out + 4194304).
// K=128, KTILES=8 both halves. Per wave per row the 64 lanes cover 16 rows
// x 128 contiguous bytes -> fully coalesced; no transpose pass needed.
// ---------------------------------------------------------------------------
__global__ __launch_bounds__(256, 3) void gemm_head2(
    const float* __restrict__ a1c, const float* __restrict__ a1t,
    const float* __restrict__ wtbase,
    const float* __restrict__ cb2, const float* __restrict__ tb2,
    float* __restrict__ outbase) {
  __shared__ float alds[16 * 128];
  __shared__ float wlds[16 * 128];
  int bid = blockIdx.x;
  bool isC = bid < 256;
  const float* in_t = isC ? a1c : a1t;
  const float* wt   = isC ? (wtbase + 26752) : (wtbase + 51328);
  const float* bias = isC ? cb2 : tb2;
  float* out        = isC ? outbase : (outbase + 4194304);
  int m0 = (bid & 255) * 128;
  int t = threadIdx.x;
  int tm = t & 15;
  int tn = t >> 4;
  float acc[8][8];
#pragma unroll
  for (int j = 0; j < 8; j++) {
    float b = bias[tn * 8 + j];
#pragma unroll
    for (int i = 0; i < 8; i++) acc[j][i] = b;
  }
  for (int kt = 0; kt < 8; kt++) {
    int k0 = kt * 16;
    __syncthreads();
#pragma unroll
    for (int pp = 0; pp < 2; pp++) {
      int e = pp * 256 + t;
      int kk = e >> 5;
      int m4 = e & 31;
      float4 v = *(const float4*)(in_t + (size_t)(k0 + kk) * PTS + m0 + m4 * 4);
      *(float4*)(alds + kk * 128 + m4 * 4) = v;
    }
#pragma unroll
    for (int pp = 0; pp < 2; pp++) {
      int e = pp * 256 + t;
      int n = e >> 2;
      int kc = e & 3;
      float4 v = *(const float4*)(wt + (size_t)n * 128 + k0 + kc * 4);
      wlds[(kc * 4 + 0) * 128 + n] = v.x;
      wlds[(kc * 4 + 1) * 128 + n] = v.y;
      wlds[(kc * 4 + 2) * 128 + n] = v.z;
      wlds[(kc * 4 + 3) * 128 + n] = v.w;
    }
    __syncthreads();
#pragma unroll
    for (int kk = 0; kk < 16; kk++) {
      float af[8], wf[8];
      *(float4*)(af)     = *(const float4*)(alds + kk * 128 + tm * 8);
      *(float4*)(af + 4) = *(const float4*)(alds + kk * 128 + tm * 8 + 4);
      *(float4*)(wf)     = *(const float4*)(wlds + kk * 128 + tn * 8);
      *(float4*)(wf + 4) = *(const float4*)(wlds + kk * 128 + tn * 8 + 4);
#pragma unroll
      for (int j = 0; j < 8; j++)
#pragma unroll
        for (int i = 0; i < 8; i++)
          acc[j][i] = fmaf(af[i], wf[j], acc[j][i]);
    }
  }
  // Transposed (row-major) epilogue: 8 rows x 2 float4 per thread.
#pragma unroll
  for (int i = 0; i < 8; i++) {
    int m = m0 + tm * 8 + i;
    float4 o0, o1;
    o0.x = fmaxf(acc[0][i], 0.f); o0.y = fmaxf(acc[1][i], 0.f);
    o0.z = fmaxf(acc[2][i], 0.f); o0.w = fmaxf(acc[3][i], 0.f);
    o1.x = fmaxf(acc[4][i], 0.f); o1.y = fmaxf(acc[5][i], 0.f);
    o1.z = fmaxf(acc[6][i], 0.f); o1.w = fmaxf(acc[7][i], 0.f);
    float* dst = out + (size_t)m * 128 + tn * 8;
    *(float4*)(dst) = o0;
    *(float4*)(dst + 4) = o1;
  }
}

// ---------------------------------------------------------------------------
extern "C" void kernel_launch(void* const* d_in, const int* in_sizes, int n_in,
                              void* d_out, int out_size, void* d_ws, size_t ws_size,
                              hipStream_t stream) {
  const float* x   = (const float*)d_in[0];
  const float* lb1 = (const float*)d_in[2];
  const float* lb2 = (const float*)d_in[4];
  const float* lb3 = (const float*)d_in[6];
  const float* cb1 = (const float*)d_in[8];
  const float* cb2 = (const float*)d_in[10];
  const float* tb1 = (const float*)d_in[12];
  const float* tb2 = (const float*)d_in[14];

  float* out = (float*)d_out;
  float* angle_out = out + 8388608;
  float* axes_out  = out + 8421376;

  // Workspace (floats), lifetime-overlapped:
  //   wt    [67712]
  //   R1    [10485760]  ipart (knn->merge, 2M u32 used)
  //   R2    [10485760]  a1c [0..4194303], a1t [4194304..8388607]
  //   R3    [20971520]  h2 (l2->l3max)
  //   lftx  [2621440]
  //   lcct2 [327680]    interleaved (l0,l1) per row
  float* W = (float*)d_ws;
  float* wt    = W;
  float* R1    = W + 67712;
  float* R2    = R1 + 10485760;
  float* R3    = R2 + 10485760;
  float* lftx  = R3 + 20971520;
  float* lcct2 = lftx + 2621440;
  unsigned int* ipart = (unsigned int*)R1;
  float* a1c   = R2;
  float* a1t   = R2 + 4194304;
  float* h2    = R3;

  prep_w<<<7, 256, 0, stream>>>((const float*)d_in[1], (const float*)d_in[3], (const float*)d_in[5],
                                (const float*)d_in[7], (const float*)d_in[9],
                                (const float*)d_in[11], (const float*)d_in[13], wt);
  knn_scan<<<1024, 256, 0, stream>>>(x, ipart);
  merge_geom<<<256, 128, 0, stream>>>(x, ipart, (float2*)lcct2, angle_out, (float2*)axes_out, lftx);

  gemm_l2<<<ROWS / 128, 256, 0, stream>>>((const float2*)lcct2, wt + 0, lb1,
                                          wt + 128, lb2, h2, ROWS);
  gemm_l3max<<<PTS / 64, 512, 0, stream>>>(h2, wt + 8320, lb3, lftx);

  gemm_head1<<<512, 256, 0, stream>>>(lftx, wt, cb1, tb1, a1c, a1t);
  gemm_head2<<<512, 256, 0, stream>>>(a1c, a1t, wt, cb2, tb2, out);
}